// Round 9
// baseline (112.429 us; speedup 1.0000x reference)
//
#include <hip/hip_runtime.h>

#define NDIR  6
#define B_    16
#define N_IN  16384
#define N_OUT 8192
#define IDIM  128
#define ODIM  128
#define TOTAL (B_ * N_OUT)   // 131072 nodes
#define BM    128            // nodes per block (4 waves x 32 rows)
#define MAXBLK (TOTAL / BM + NDIR)   // 1030

// d_ws layout (ints): [0..7]=cnt, [8..14]=node offsets, [16..23]=cursors,
// [24..30]=block offsets, ids at int 64 (131072 ints),
// Wt (bf16 hi/lo, transposed frag layout) at int 131584.
#define WS_CNT 0
#define WS_OFF 8
#define WS_CUR 16
#define WS_BLK 24
#define WS_IDS 64
#define WS_WT  131584

using s16x8 = __attribute__((ext_vector_type(8))) short;   // 8 bf16 (4 VGPR)
using f32x4 = __attribute__((ext_vector_type(4))) float;   // acc frag

__global__ void zero_kernel(int* ws) {
    int t = threadIdx.x;
    if (t < 32) ws[t] = 0;
}

__global__ void count_kernel(const int* __restrict__ vec, const int* __restrict__ dmap,
                             int* __restrict__ ws) {
    __shared__ int h[NDIR];
    int t = threadIdx.x;
    if (t < NDIR) h[t] = 0;
    __syncthreads();
    int id = blockIdx.x * 256 + t;
    if (id < TOTAL) {
        int d = dmap[vec[id]];
        atomicAdd(&h[d], 1);
    }
    __syncthreads();
    if (t < NDIR && h[t]) atomicAdd(&ws[WS_CNT + t], h[t]);
}

__global__ void prefix_kernel(int* ws) {
    if (threadIdx.x == 0) {
        int acc = 0, bacc = 0;
        for (int i = 0; i < NDIR; ++i) {
            ws[WS_OFF + i] = acc;
            ws[WS_CUR + i] = acc;
            ws[WS_BLK + i] = bacc;
            int c = ws[WS_CNT + i];
            acc += c;
            bacc += (c + BM - 1) / BM;
        }
        ws[WS_OFF + NDIR] = acc;
        ws[WS_BLK + NDIR] = bacc;
    }
}

__global__ void scatter_kernel(const int* __restrict__ vec, const int* __restrict__ dmap,
                               int* __restrict__ ws) {
    __shared__ int h[NDIR];
    __shared__ int base[NDIR];
    int t = threadIdx.x;
    if (t < NDIR) h[t] = 0;
    __syncthreads();
    int id = blockIdx.x * 256 + t;
    int d = 0, pos = 0;
    if (id < TOTAL) {
        d = dmap[vec[id]];
        pos = atomicAdd(&h[d], 1);
    }
    __syncthreads();
    if (t < NDIR) base[t] = h[t] ? atomicAdd(&ws[WS_CUR + t], h[t]) : 0;
    __syncthreads();
    if (id < TOTAL) ws[WS_IDS + base[d] + pos] = id;
}

// Pre-transpose + bf16-split W into d_ws, in MFMA B-fragment order.
// Per (dir d, kstep s): 16KB block = hi[col 0..127][k 0..31] bf16 (8KB)
// then lo (8KB). Lane l of a wave reads its fragment for column `col`,
// k-chunk l>>4 as ONE contiguous 16B load at short-index col*32+(l>>4)*8.
__global__ void wconvert_kernel(const float* __restrict__ W, int* __restrict__ ws) {
    unsigned short* wt = (unsigned short*)(ws + WS_WT);
    int g = blockIdx.x * 256 + threadIdx.x;      // 0..196607
    int dsb = g >> 12;                           // d*8+s, 0..47
    int e = g & 4095;
    int col = e >> 5;
    int kk = e & 31;
    int d = dsb >> 3, s = dsb & 7;
    float w = W[((d * 256) + s * 32 + kk) * 128 + col];
    unsigned u = __float_as_uint(w);
    float hf = __uint_as_float(u & 0xFFFF0000u);
    float lf = w - hf;
    int base = dsb * 8192 + col * 32 + kk;
    wt[base] = (unsigned short)(u >> 16);
    wt[base + 4096] = (unsigned short)(__float_as_uint(lf) >> 16);
}

__device__ __forceinline__ void cvt8(float4 a, float4 b, s16x8& h, s16x8& lo) {
    float x[8] = {a.x, a.y, a.z, a.w, b.x, b.y, b.z, b.w};
    #pragma unroll
    for (int j = 0; j < 8; ++j) {
        unsigned u = __float_as_uint(x[j]);
        float hf = __uint_as_float(u & 0xFFFF0000u);
        float lf = x[j] - hf;
        h[j] = (short)(u >> 16);
        lo[j] = (short)(__float_as_uint(lf) >> 16);
    }
}

// MFMA gather-GEMM, barrier-free K-loop: block = 128 nodes x 128 outputs,
// 4 waves (32 rows each), K=256 in 8 steps of 32. fp32 via 3x bf16 MFMA
// (hh + hl + lh). B-fragments read DIRECTLY from global (Wt is 768KB total,
// L2-resident on every XCD) -> no LDS staging, no __syncthreads in the loop,
// no vmcnt(0) drains: A-gather and B-loads pipeline freely across K-steps.
__global__ __launch_bounds__(256, 2) void gemm_kernel(
    const float* __restrict__ last, const float* __restrict__ bias,
    const float* __restrict__ alphap,
    const int* __restrict__ vec, const int* __restrict__ drev,
    const int* __restrict__ child_l, const int* __restrict__ child_r,
    const int* __restrict__ ws, float* __restrict__ out)
{
    int i = blockIdx.x;
    if (i >= ws[WS_BLK + NDIR]) return;
    int dir = 0;
    #pragma unroll
    for (int d = 1; d < NDIR; ++d)
        if (i >= ws[WS_BLK + d]) dir = d;
    int tile = i - ws[WS_BLK + dir];
    int start = ws[WS_OFF + dir];
    int end   = ws[WS_OFF + dir + 1];
    int m0 = start + tile * BM;
    const int* ids = ws + WS_IDS;

    __shared__ int s_row0[BM], s_row1[BM], s_oid[BM];

    int t = threadIdx.x;
    int l = t & 63;
    int wid = t >> 6;

    if (t < BM) {
        int idx = m0 + t;
        bool valid = idx < end;
        int id = ids[valid ? idx : end - 1];
        int b = id >> 13;            // N_OUT = 8192
        int n = id & (N_OUT - 1);
        int v = vec[id];
        int r = drev[v];
        int cl = child_l[n];
        int cr = child_r[n];
        int first  = r ? cr : cl;
        int second = r ? cl : cr;
        s_row0[t] = b * N_IN + first;
        s_row1[t] = b * N_IN + second;
        s_oid[t]  = valid ? id : -1;
    }
    __syncthreads();   // the only block-wide barrier

    // hoist row indices into registers
    int rowA[2][2];
    #pragma unroll
    for (int f = 0; f < 2; ++f) {
        int m = wid * 32 + f * 16 + (l & 15);
        rowA[0][f] = s_row0[m];
        rowA[1][f] = s_row1[m];
    }

    f32x4 acc[2][8];
    #pragma unroll
    for (int f = 0; f < 2; ++f)
        #pragma unroll
        for (int nf = 0; nf < 8; ++nf)
            acc[f][nf] = (f32x4){0.f, 0.f, 0.f, 0.f};

    // B-fragment base for this lane: hi at wt_dir + s*16384 + col*64 + (l>>4)*16
    const char* wt_dir = (const char*)(ws + WS_WT) + (size_t)dir * 8 * 16384;
    const char* wl = wt_dir + ((l & 15) * 64 + (l >> 4) * 16);

    // prologue: issue A-gather for step 0
    float4 xa0[2], xa1[2];
    #pragma unroll
    for (int f = 0; f < 2; ++f) {
        const float* src = last + (size_t)rowA[0][f] * IDIM + (l >> 4) * 8;
        xa0[f] = *(const float4*)src;
        xa1[f] = *(const float4*)(src + 4);
    }

    #pragma unroll
    for (int s = 0; s < 8; ++s) {
        // --- consume prefetched A: convert to bf16 hi/lo
        s16x8 ah[2], al[2];
        #pragma unroll
        for (int f = 0; f < 2; ++f) cvt8(xa0[f], xa1[f], ah[f], al[f]);
        // --- issue A-gather for step s+1 (no barrier ahead: truly overlaps)
        if (s < 7) {
            #pragma unroll
            for (int f = 0; f < 2; ++f) {
                const float* src = last + (size_t)rowA[(s + 1) >> 2][f] * IDIM
                                 + ((s + 1) & 3) * 32 + (l >> 4) * 8;
                xa0[f] = *(const float4*)src;
                xa1[f] = *(const float4*)(src + 4);
            }
        }
        // --- B frags straight from global (L2-resident), 3-term split MFMA
        const char* wstep = wl + s * 16384;
        #pragma unroll
        for (int nf = 0; nf < 8; ++nf) {
            s16x8 bh = *(const s16x8*)(wstep + nf * 1024);
            s16x8 bl = *(const s16x8*)(wstep + nf * 1024 + 8192);
            #pragma unroll
            for (int f = 0; f < 2; ++f) {
                acc[f][nf] = __builtin_amdgcn_mfma_f32_16x16x32_bf16(ah[f], bh, acc[f][nf], 0, 0, 0);
                acc[f][nf] = __builtin_amdgcn_mfma_f32_16x16x32_bf16(ah[f], bl, acc[f][nf], 0, 0, 0);
                acc[f][nf] = __builtin_amdgcn_mfma_f32_16x16x32_bf16(al[f], bh, acc[f][nf], 0, 0, 0);
            }
        }
    }

    // --- epilogue: D frag row=(l>>4)*4+j, col=l&15 (m89/m91 verified)
    float alpha = alphap[0];
    #pragma unroll
    for (int nf = 0; nf < 8; ++nf) {
        int col = nf * 16 + (l & 15);
        float bv = bias[dir * ODIM + col];
        #pragma unroll
        for (int f = 0; f < 2; ++f) {
            #pragma unroll
            for (int j = 0; j < 4; ++j) {
                int mloc = wid * 32 + f * 16 + (l >> 4) * 4 + j;
                int id = s_oid[mloc];
                if (id < 0) continue;
                float y = acc[f][nf][j] + bv;
                out[(size_t)id * ODIM + col] = y >= 0.f ? y : alpha * y;
            }
        }
    }
}

extern "C" void kernel_launch(void* const* d_in, const int* in_sizes, int n_in,
                              void* d_out, int out_size, void* d_ws, size_t ws_size,
                              hipStream_t stream) {
    const float* last    = (const float*)d_in[0];
    const float* W       = (const float*)d_in[1];
    const float* bias    = (const float*)d_in[2];
    const float* alpha   = (const float*)d_in[3];
    const int*   vec     = (const int*)d_in[4];
    const int*   dmap    = (const int*)d_in[5];
    const int*   drev    = (const int*)d_in[6];
    const int*   child_l = (const int*)d_in[7];
    const int*   child_r = (const int*)d_in[8];
    float* out = (float*)d_out;
    int*   ws  = (int*)d_ws;

    zero_kernel<<<1, 64, 0, stream>>>(ws);
    count_kernel<<<TOTAL / 256, 256, 0, stream>>>(vec, dmap, ws);
    prefix_kernel<<<1, 64, 0, stream>>>(ws);
    scatter_kernel<<<TOTAL / 256, 256, 0, stream>>>(vec, dmap, ws);
    wconvert_kernel<<<(NDIR * 8 * 4096) / 256, 256, 0, stream>>>(W, ws);
    gemm_kernel<<<MAXBLK, 256, 0, stream>>>(last, bias, alpha, vec, drev,
                                            child_l, child_r, ws, out);
}

// Round 10
// 81.991 us; speedup vs baseline: 1.3712x; 1.3712x over previous
//
#include <hip/hip_runtime.h>

#define NDIR  6
#define B_    16
#define N_IN  16384
#define N_OUT 8192
#define IDIM  128
#define ODIM  128
#define TOTAL (B_ * N_OUT)   // 131072 nodes
#define BM    128            // nodes per block (4 waves x 32 rows)
#define MAXBLK (TOTAL / BM + NDIR)   // 1030

// d_ws layout (ints): [0..7]=cnt, [8..14]=node offsets, [16..23]=cursors,
// [24..30]=block offsets, ids at int 64, Wt (bf16 hi/lo swizzled) at 131584.
#define WS_CNT 0
#define WS_OFF 8
#define WS_CUR 16
#define WS_BLK 24
#define WS_IDS 64
#define WS_WT  131584

using s16x8 = __attribute__((ext_vector_type(8))) short;   // 8 bf16 (4 VGPR)
using f32x4 = __attribute__((ext_vector_type(4))) float;   // acc frag

__global__ void zero_kernel(int* ws) {
    int t = threadIdx.x;
    if (t < 32) ws[t] = 0;
}

__global__ void count_kernel(const int* __restrict__ vec, const int* __restrict__ dmap,
                             int* __restrict__ ws) {
    __shared__ int h[NDIR];
    int t = threadIdx.x;
    if (t < NDIR) h[t] = 0;
    __syncthreads();
    int id = blockIdx.x * 256 + t;
    if (id < TOTAL) {
        int d = dmap[vec[id]];
        atomicAdd(&h[d], 1);
    }
    __syncthreads();
    if (t < NDIR && h[t]) atomicAdd(&ws[WS_CNT + t], h[t]);
}

__global__ void prefix_kernel(int* ws) {
    if (threadIdx.x == 0) {
        int acc = 0, bacc = 0;
        for (int i = 0; i < NDIR; ++i) {
            ws[WS_OFF + i] = acc;
            ws[WS_CUR + i] = acc;
            ws[WS_BLK + i] = bacc;
            int c = ws[WS_CNT + i];
            acc += c;
            bacc += (c + BM - 1) / BM;
        }
        ws[WS_OFF + NDIR] = acc;
        ws[WS_BLK + NDIR] = bacc;
    }
}

__global__ void scatter_kernel(const int* __restrict__ vec, const int* __restrict__ dmap,
                               int* __restrict__ ws) {
    __shared__ int h[NDIR];
    __shared__ int base[NDIR];
    int t = threadIdx.x;
    if (t < NDIR) h[t] = 0;
    __syncthreads();
    int id = blockIdx.x * 256 + t;
    int d = 0, pos = 0;
    if (id < TOTAL) {
        d = dmap[vec[id]];
        pos = atomicAdd(&h[d], 1);
    }
    __syncthreads();
    if (t < NDIR) base[t] = h[t] ? atomicAdd(&ws[WS_CUR + t], h[t]) : 0;
    __syncthreads();
    if (id < TOTAL) ws[WS_IDS + base[d] + pos] = id;
}

// Pre-transpose + bf16-split + swizzle W into d_ws (R7 layout; 0 conflicts).
// Per (dir d, kstep s): 16KB = hi[col][chunk'][i] (8KB) then lo (8KB);
// stored chunk c' holds source chunk c'^key, key(col) = (col>>1)&3.
__global__ void wconvert_kernel(const float* __restrict__ W, int* __restrict__ ws) {
    unsigned short* wt = (unsigned short*)(ws + WS_WT);
    int g = blockIdx.x * 256 + threadIdx.x;      // 0..196607
    int dsb = g >> 12;                           // d*8+s, 0..47
    int e = g & 4095;
    int col = e >> 5;
    int kk = e & 31;
    int cp = kk >> 3, i = kk & 7;
    int key = (col >> 1) & 3;
    int d = dsb >> 3, s = dsb & 7;
    int ksrc = s * 32 + ((cp ^ key) << 3) + i;
    float w = W[((d * 256) + ksrc) * 128 + col];
    unsigned u = __float_as_uint(w);
    float hf = __uint_as_float(u & 0xFFFF0000u);
    float lf = w - hf;
    int base = dsb * 8192 + col * 32 + cp * 8 + i;
    wt[base] = (unsigned short)(u >> 16);
    wt[base + 4096] = (unsigned short)(__float_as_uint(lf) >> 16);
}

__device__ __forceinline__ void cvt8(float4 a, float4 b, s16x8& h, s16x8& lo) {
    float x[8] = {a.x, a.y, a.z, a.w, b.x, b.y, b.z, b.w};
    #pragma unroll
    for (int j = 0; j < 8; ++j) {
        unsigned u = __float_as_uint(x[j]);
        float hf = __uint_as_float(u & 0xFFFF0000u);
        float lf = x[j] - hf;
        h[j] = (short)(u >> 16);
        lo[j] = (short)(__float_as_uint(lf) >> 16);
    }
}

#define CFENCE() asm volatile("" ::: "memory")

// MFMA gather-GEMM with counted-vmcnt pipeline (no vmcnt(0) drain in loop):
// per iter t: [issue STAGE_{t+1}] [vmcnt(8): A_t,S_t done] [s_barrier #1]
// [cvt A_t] [issue A_{t+2}] [ds_read + 48 MFMA] [s_barrier #2].
// Queue (oldest->newest) entering t: A_t, S_t, A_{t+1}; after S-issue: +S_{t+1}
// -> vmcnt(8) leaves {A_{t+1}, S_{t+1}}. A gets ~2 iters of latency coverage.
__global__ __launch_bounds__(256, 3) void gemm_kernel(
    const float* __restrict__ last, const float* __restrict__ bias,
    const float* __restrict__ alphap,
    const int* __restrict__ vec, const int* __restrict__ drev,
    const int* __restrict__ child_l, const int* __restrict__ child_r,
    const int* __restrict__ ws, float* __restrict__ out)
{
    int i = blockIdx.x;
    if (i >= ws[WS_BLK + NDIR]) return;
    int dir = 0;
    #pragma unroll
    for (int d = 1; d < NDIR; ++d)
        if (i >= ws[WS_BLK + d]) dir = d;
    int tile = i - ws[WS_BLK + dir];
    int start = ws[WS_OFF + dir];
    int end   = ws[WS_OFF + dir + 1];
    int m0 = start + tile * BM;
    const int* ids = ws + WS_IDS;

    __shared__ unsigned short wbuf[2][8192];   // 2 x 16KB W tiles
    __shared__ int s_row0[BM], s_row1[BM], s_oid[BM];

    int t = threadIdx.x;
    int l = t & 63;
    int wid = t >> 6;

    if (t < BM) {
        int idx = m0 + t;
        bool valid = idx < end;
        int id = ids[valid ? idx : end - 1];
        int b = id >> 13;            // N_OUT = 8192
        int n = id & (N_OUT - 1);
        int v = vec[id];
        int r = drev[v];
        int cl = child_l[n];
        int cr = child_r[n];
        int first  = r ? cr : cl;
        int second = r ? cl : cr;
        s_row0[t] = b * N_IN + first;
        s_row1[t] = b * N_IN + second;
        s_oid[t]  = valid ? id : -1;
    }
    __syncthreads();   // once, before the pipeline starts

    // hoist row indices into registers
    int rowA[2][2];
    #pragma unroll
    for (int f = 0; f < 2; ++f) {
        int m = wid * 32 + f * 16 + (l & 15);
        rowA[0][f] = s_row0[m];
        rowA[1][f] = s_row1[m];
    }

    const char* wt_blk = (const char*)(ws + WS_WT) + (size_t)dir * 8 * 16384;

    #define STAGE_W(buf, s_)                                                     \
        {                                                                        \
            const char* gsrc = wt_blk + (size_t)(s_) * 16384 + wid * 4096 + l * 16; \
            char* ldst = (char*)&wbuf[buf][0] + wid * 4096;                      \
            _Pragma("unroll")                                                    \
            for (int i_ = 0; i_ < 4; ++i_) {                                     \
                __builtin_amdgcn_global_load_lds(                                \
                    (const __attribute__((address_space(1))) void*)(gsrc + i_ * 1024), \
                    (__attribute__((address_space(3))) void*)(ldst + i_ * 1024), \
                    16, 0, 0);                                                   \
            }                                                                    \
        }

    #define ISSUE_A(buf, s_)                                                     \
        {                                                                        \
            _Pragma("unroll")                                                    \
            for (int f_ = 0; f_ < 2; ++f_) {                                     \
                const float* src = last + (size_t)rowA[(s_) >> 2][f_] * IDIM     \
                                 + ((s_) & 3) * 32 + (l >> 4) * 8;               \
                xa0[buf][f_] = *(const float4*)src;                              \
                xa1[buf][f_] = *(const float4*)(src + 4);                        \
            }                                                                    \
        }

    f32x4 acc[2][8];
    #pragma unroll
    for (int f = 0; f < 2; ++f)
        #pragma unroll
        for (int nf = 0; nf < 8; ++nf)
            acc[f][nf] = (f32x4){0.f, 0.f, 0.f, 0.f};

    float4 xa0[2][2], xa1[2][2];   // 2-deep A ring (all indices static)

    // prologue: queue = [S0, A0, A1]
    STAGE_W(0, 0);
    CFENCE();
    ISSUE_A(0, 0);
    ISSUE_A(1, 1);
    CFENCE();

    #pragma unroll
    for (int s = 0; s < 8; ++s) {
        int cur = s & 1;
        // --- issue STAGE_{s+1} (buffer protected by barrier #2 of iter s-1)
        if (s < 7) { STAGE_W(cur ^ 1, s + 1); CFENCE(); }
        // --- counted wait: A_s and S_s complete; later loads stay in flight
        if (s < 7) { asm volatile("s_waitcnt vmcnt(8)" ::: "memory"); }
        else       { asm volatile("s_waitcnt vmcnt(0)" ::: "memory"); }
        __builtin_amdgcn_s_barrier();   // #1: buf[cur] staged by ALL waves
        CFENCE();
        // --- consume A_s
        s16x8 ah[2], al[2];
        #pragma unroll
        for (int f = 0; f < 2; ++f) cvt8(xa0[cur][f], xa1[cur][f], ah[f], al[f]);
        // --- issue A_{s+2} into the ring slot just freed
        if (s < 6) { CFENCE(); ISSUE_A(cur, s + 2); CFENCE(); }
        // --- B frags in quarters + 3-term split MFMA
        #pragma unroll
        for (int q = 0; q < 4; ++q) {
            s16x8 bh[2], bl[2];
            #pragma unroll
            for (int i2 = 0; i2 < 2; ++i2) {
                int nf = q * 2 + i2;
                int col = nf * 16 + (l & 15);
                int cp = (l >> 4) ^ ((col >> 1) & 3);
                int off = col * 32 + cp * 8;          // shorts
                bh[i2] = *(const s16x8*)&wbuf[cur][off];
                bl[i2] = *(const s16x8*)&wbuf[cur][off + 4096];
            }
            #pragma unroll
            for (int f = 0; f < 2; ++f) {
                #pragma unroll
                for (int i2 = 0; i2 < 2; ++i2) {
                    int nf = q * 2 + i2;
                    acc[f][nf] = __builtin_amdgcn_mfma_f32_16x16x32_bf16(ah[f], bh[i2], acc[f][nf], 0, 0, 0);
                    acc[f][nf] = __builtin_amdgcn_mfma_f32_16x16x32_bf16(ah[f], bl[i2], acc[f][nf], 0, 0, 0);
                    acc[f][nf] = __builtin_amdgcn_mfma_f32_16x16x32_bf16(al[f], bh[i2], acc[f][nf], 0, 0, 0);
                }
            }
        }
        // --- #2: all waves done reading buf[cur]; next iter may stage into it
        if (s < 7) {
            CFENCE();
            __builtin_amdgcn_s_barrier();
            CFENCE();
        }
    }

    // --- epilogue: D frag row=(l>>4)*4+j, col=l&15 (m89/m91 verified)
    float alpha = alphap[0];
    #pragma unroll
    for (int nf = 0; nf < 8; ++nf) {
        int col = nf * 16 + (l & 15);
        float bv = bias[dir * ODIM + col];
        #pragma unroll
        for (int f = 0; f < 2; ++f) {
            #pragma unroll
            for (int j = 0; j < 4; ++j) {
                int mloc = wid * 32 + f * 16 + (l >> 4) * 4 + j;
                int id = s_oid[mloc];
                if (id < 0) continue;
                float y = acc[f][nf][j] + bv;
                out[(size_t)id * ODIM + col] = y >= 0.f ? y : alpha * y;
            }
        }
    }
    #undef STAGE_W
    #undef ISSUE_A
}

extern "C" void kernel_launch(void* const* d_in, const int* in_sizes, int n_in,
                              void* d_out, int out_size, void* d_ws, size_t ws_size,
                              hipStream_t stream) {
    const float* last    = (const float*)d_in[0];
    const float* W       = (const float*)d_in[1];
    const float* bias    = (const float*)d_in[2];
    const float* alpha   = (const float*)d_in[3];
    const int*   vec     = (const int*)d_in[4];
    const int*   dmap    = (const int*)d_in[5];
    const int*   drev    = (const int*)d_in[6];
    const int*   child_l = (const int*)d_in[7];
    const int*   child_r = (const int*)d_in[8];
    float* out = (float*)d_out;
    int*   ws  = (int*)d_ws;

    zero_kernel<<<1, 64, 0, stream>>>(ws);
    count_kernel<<<TOTAL / 256, 256, 0, stream>>>(vec, dmap, ws);
    prefix_kernel<<<1, 64, 0, stream>>>(ws);
    scatter_kernel<<<TOTAL / 256, 256, 0, stream>>>(vec, dmap, ws);
    wconvert_kernel<<<(NDIR * 8 * 4096) / 256, 256, 0, stream>>>(W, ws);
    gemm_kernel<<<MAXBLK, 256, 0, stream>>>(last, bias, alpha, vec, drev,
                                            child_l, child_r, ws, out);
}

// Round 12
// 81.517 us; speedup vs baseline: 1.3792x; 1.0058x over previous
//
#include <hip/hip_runtime.h>

#define NDIR  6
#define B_    16
#define N_IN  16384
#define N_OUT 8192
#define IDIM  128
#define ODIM  128
#define TOTAL (B_ * N_OUT)   // 131072 nodes
#define BM    64             // nodes per block (4 waves x 16 rows)
#define MAXBLK (TOTAL / BM + NDIR)   // 2054

// d_ws layout (ints): [0..7]=cnt, [8..14]=node offsets, [16..23]=cursors,
// [24..30]=block offsets, ids at int 64, Wt (bf16 hi/lo swizzled) at 131584.
#define WS_CNT 0
#define WS_OFF 8
#define WS_CUR 16
#define WS_BLK 24
#define WS_IDS 64
#define WS_WT  131584

using s16x8 = __attribute__((ext_vector_type(8))) short;   // 8 bf16 (4 VGPR)
using f32x4 = __attribute__((ext_vector_type(4))) float;   // acc frag

__global__ void zero_kernel(int* ws) {
    int t = threadIdx.x;
    if (t < 32) ws[t] = 0;
}

__global__ void count_kernel(const int* __restrict__ vec, const int* __restrict__ dmap,
                             int* __restrict__ ws) {
    __shared__ int h[NDIR];
    int t = threadIdx.x;
    if (t < NDIR) h[t] = 0;
    __syncthreads();
    int id = blockIdx.x * 256 + t;
    if (id < TOTAL) {
        int d = dmap[vec[id]];
        atomicAdd(&h[d], 1);
    }
    __syncthreads();
    if (t < NDIR && h[t]) atomicAdd(&ws[WS_CNT + t], h[t]);
}

__global__ void prefix_kernel(int* ws) {
    if (threadIdx.x == 0) {
        int acc = 0, bacc = 0;
        for (int i = 0; i < NDIR; ++i) {
            ws[WS_OFF + i] = acc;
            ws[WS_CUR + i] = acc;
            ws[WS_BLK + i] = bacc;
            int c = ws[WS_CNT + i];
            acc += c;
            bacc += (c + BM - 1) / BM;
        }
        ws[WS_OFF + NDIR] = acc;
        ws[WS_BLK + NDIR] = bacc;
    }
}

__global__ void scatter_kernel(const int* __restrict__ vec, const int* __restrict__ dmap,
                               int* __restrict__ ws) {
    __shared__ int h[NDIR];
    __shared__ int base[NDIR];
    int t = threadIdx.x;
    if (t < NDIR) h[t] = 0;
    __syncthreads();
    int id = blockIdx.x * 256 + t;
    int d = 0, pos = 0;
    if (id < TOTAL) {
        d = dmap[vec[id]];
        pos = atomicAdd(&h[d], 1);
    }
    __syncthreads();
    if (t < NDIR) base[t] = h[t] ? atomicAdd(&ws[WS_CUR + t], h[t]) : 0;
    __syncthreads();
    if (id < TOTAL) ws[WS_IDS + base[d] + pos] = id;
}

// Pre-transpose + bf16-split + swizzle W into d_ws (R7 layout; 0 conflicts).
// Per (dir d, kstep s): 16KB = hi[col][chunk'][i] (8KB) then lo (8KB);
// stored chunk c' holds source chunk c'^key, key(col) = (col>>1)&3.
__global__ void wconvert_kernel(const float* __restrict__ W, int* __restrict__ ws) {
    unsigned short* wt = (unsigned short*)(ws + WS_WT);
    int g = blockIdx.x * 256 + threadIdx.x;      // 0..196607
    int dsb = g >> 12;                           // d*8+s, 0..47
    int e = g & 4095;
    int col = e >> 5;
    int kk = e & 31;
    int cp = kk >> 3, i = kk & 7;
    int key = (col >> 1) & 3;
    int d = dsb >> 3, s = dsb & 7;
    int ksrc = s * 32 + ((cp ^ key) << 3) + i;
    float w = W[((d * 256) + ksrc) * 128 + col];
    unsigned u = __float_as_uint(w);
    float hf = __uint_as_float(u & 0xFFFF0000u);
    float lf = w - hf;
    int base = dsb * 8192 + col * 32 + cp * 8 + i;
    wt[base] = (unsigned short)(u >> 16);
    wt[base + 4096] = (unsigned short)(__float_as_uint(lf) >> 16);
}

__device__ __forceinline__ void cvt8(float4 a, float4 b, s16x8& h, s16x8& lo) {
    float x[8] = {a.x, a.y, a.z, a.w, b.x, b.y, b.z, b.w};
    #pragma unroll
    for (int j = 0; j < 8; ++j) {
        unsigned u = __float_as_uint(x[j]);
        float hf = __uint_as_float(u & 0xFFFF0000u);
        float lf = x[j] - hf;
        h[j] = (short)(u >> 16);
        lo[j] = (short)(__float_as_uint(lf) >> 16);
    }
}

#define CFENCE() asm volatile("" ::: "memory")

// MFMA gather-GEMM, occupancy-first: block = 64 nodes x 128 outputs, 4 waves
// of ONE 16x128 tile each (acc 32 VGPR). K=256 in 8 steps of 32; fp32 via
// 3x bf16 MFMA. Counted-vmcnt pipeline: per iter s:
// [issue STAGE_{s+1} (4 inst)] [vmcnt(6): A_s(2)+S_s(4) done] [barrier #1]
// [cvt A_s] [issue A_{s+2} (2 inst)] [ds_read + 24 MFMA] [barrier #2].
__global__ __launch_bounds__(256, 4) void gemm_kernel(
    const float* __restrict__ last, const float* __restrict__ bias,
    const float* __restrict__ alphap,
    const int* __restrict__ vec, const int* __restrict__ drev,
    const int* __restrict__ child_l, const int* __restrict__ child_r,
    const int* __restrict__ ws, float* __restrict__ out)
{
    int i = blockIdx.x;
    if (i >= ws[WS_BLK + NDIR]) return;
    int dir = 0;
    #pragma unroll
    for (int d = 1; d < NDIR; ++d)
        if (i >= ws[WS_BLK + d]) dir = d;
    int tile = i - ws[WS_BLK + dir];
    int start = ws[WS_OFF + dir];
    int end   = ws[WS_OFF + dir + 1];
    int m0 = start + tile * BM;
    const int* ids = ws + WS_IDS;

    __shared__ unsigned short wbuf[2][8192];   // 2 x 16KB W tiles
    __shared__ int s_row0[BM], s_row1[BM], s_oid[BM];

    int t = threadIdx.x;
    int l = t & 63;
    int wid = t >> 6;

    if (t < BM) {
        int idx = m0 + t;
        bool valid = idx < end;
        int id = ids[valid ? idx : end - 1];
        int b = id >> 13;            // N_OUT = 8192
        int n = id & (N_OUT - 1);
        int v = vec[id];
        int r = drev[v];
        int cl = child_l[n];
        int cr = child_r[n];
        int first  = r ? cr : cl;
        int second = r ? cl : cr;
        s_row0[t] = b * N_IN + first;
        s_row1[t] = b * N_IN + second;
        s_oid[t]  = valid ? id : -1;
    }
    __syncthreads();   // once, before the pipeline starts

    // hoist this wave's row indices (16 rows, lane&15 selects)
    int m = wid * 16 + (l & 15);
    int rowA[2] = { s_row0[m], s_row1[m] };

    const char* wt_blk = (const char*)(ws + WS_WT) + (size_t)dir * 8 * 16384;

    #define STAGE_W(buf, s_)                                                     \
        {                                                                        \
            const char* gsrc = wt_blk + (size_t)(s_) * 16384 + wid * 4096 + l * 16; \
            char* ldst = (char*)&wbuf[buf][0] + wid * 4096;                      \
            _Pragma("unroll")                                                    \
            for (int i_ = 0; i_ < 4; ++i_) {                                     \
                __builtin_amdgcn_global_load_lds(                                \
                    (const __attribute__((address_space(1))) void*)(gsrc + i_ * 1024), \
                    (__attribute__((address_space(3))) void*)(ldst + i_ * 1024), \
                    16, 0, 0);                                                   \
            }                                                                    \
        }

    // 2 loads per step: lane reads 8 floats of row rowA[s>>2], chunk (l>>4)
    #define ISSUE_A(buf, s_)                                                     \
        {                                                                        \
            const float* src = last + (size_t)rowA[(s_) >> 2] * IDIM             \
                             + ((s_) & 3) * 32 + (l >> 4) * 8;                   \
            xa0[buf] = *(const float4*)src;                                      \
            xa1[buf] = *(const float4*)(src + 4);                                \
        }

    f32x4 acc[8];
    #pragma unroll
    for (int nf = 0; nf < 8; ++nf)
        acc[nf] = (f32x4){0.f, 0.f, 0.f, 0.f};

    float4 xa0[2], xa1[2];   // 2-deep A ring (static indices)

    // prologue: queue = [S0(4), A0(2), A1(2)]
    STAGE_W(0, 0);
    CFENCE();
    ISSUE_A(0, 0);
    ISSUE_A(1, 1);
    CFENCE();

    #pragma unroll
    for (int s = 0; s < 8; ++s) {
        int cur = s & 1;
        // --- issue STAGE_{s+1} (buffer protected by barrier #2 of iter s-1)
        if (s < 7) { STAGE_W(cur ^ 1, s + 1); CFENCE(); }
        // --- counted wait: A_s(2)+S_s(4) complete; A_{s+1}(2)+S_{s+1}(4) in flight
        if (s < 7) { asm volatile("s_waitcnt vmcnt(6)" ::: "memory"); }
        else       { asm volatile("s_waitcnt vmcnt(0)" ::: "memory"); }
        __builtin_amdgcn_s_barrier();   // #1: buf[cur] staged by ALL waves
        CFENCE();
        // --- consume A_s
        s16x8 ah, al;
        cvt8(xa0[cur], xa1[cur], ah, al);
        // --- issue A_{s+2} into the ring slot just freed
        if (s < 6) { CFENCE(); ISSUE_A(cur, s + 2); CFENCE(); }
        // --- B frags in quarters + 3-term split MFMA (24 MFMA/step)
        #pragma unroll
        for (int q = 0; q < 4; ++q) {
            s16x8 bh[2], bl[2];
            #pragma unroll
            for (int i2 = 0; i2 < 2; ++i2) {
                int nf = q * 2 + i2;
                int col = nf * 16 + (l & 15);
                int cp = (l >> 4) ^ ((col >> 1) & 3);
                int off = col * 32 + cp * 8;          // shorts
                bh[i2] = *(const s16x8*)&wbuf[cur][off];
                bl[i2] = *(const s16x8*)&wbuf[cur][off + 4096];
            }
            #pragma unroll
            for (int i2 = 0; i2 < 2; ++i2) {
                int nf = q * 2 + i2;
                acc[nf] = __builtin_amdgcn_mfma_f32_16x16x32_bf16(ah, bh[i2], acc[nf], 0, 0, 0);
                acc[nf] = __builtin_amdgcn_mfma_f32_16x16x32_bf16(ah, bl[i2], acc[nf], 0, 0, 0);
                acc[nf] = __builtin_amdgcn_mfma_f32_16x16x32_bf16(al, bh[i2], acc[nf], 0, 0, 0);
            }
        }
        // --- #2: all waves done reading buf[cur]; next iter may stage into it
        if (s < 7) {
            CFENCE();
            __builtin_amdgcn_s_barrier();
            CFENCE();
        }
    }

    // --- epilogue: D frag row=(l>>4)*4+j, col=l&15 (m89/m91 verified)
    float alpha = alphap[0];
    #pragma unroll
    for (int nf = 0; nf < 8; ++nf) {
        int col = nf * 16 + (l & 15);
        float bv = bias[dir * ODIM + col];
        #pragma unroll
        for (int j = 0; j < 4; ++j) {
            int mloc = wid * 16 + (l >> 4) * 4 + j;
            int id = s_oid[mloc];
            if (id < 0) continue;
            float y = acc[nf][j] + bv;
            out[(size_t)id * ODIM + col] = y >= 0.f ? y : alpha * y;
        }
    }
    #undef STAGE_W
    #undef ISSUE_A
}

extern "C" void kernel_launch(void* const* d_in, const int* in_sizes, int n_in,
                              void* d_out, int out_size, void* d_ws, size_t ws_size,
                              hipStream_t stream) {
    const float* last    = (const float*)d_in[0];
    const float* W       = (const float*)d_in[1];
    const float* bias    = (const float*)d_in[2];
    const float* alpha   = (const float*)d_in[3];
    const int*   vec     = (const int*)d_in[4];
    const int*   dmap    = (const int*)d_in[5];
    const int*   drev    = (const int*)d_in[6];
    const int*   child_l = (const int*)d_in[7];
    const int*   child_r = (const int*)d_in[8];
    float* out = (float*)d_out;
    int*   ws  = (int*)d_ws;

    zero_kernel<<<1, 64, 0, stream>>>(ws);
    count_kernel<<<TOTAL / 256, 256, 0, stream>>>(vec, dmap, ws);
    prefix_kernel<<<1, 64, 0, stream>>>(ws);
    scatter_kernel<<<TOTAL / 256, 256, 0, stream>>>(vec, dmap, ws);
    wconvert_kernel<<<(NDIR * 8 * 4096) / 256, 256, 0, stream>>>(W, ws);
    gemm_kernel<<<MAXBLK, 256, 0, stream>>>(last, bias, alpha, vec, drev,
                                            child_l, child_r, ws, out);
}